// Round 10
// baseline (98.833 us; speedup 1.0000x reference)
//
#include <hip/hip_runtime.h>
#include <hip/hip_bf16.h>

#define N 8192
#define D 128
#define LOG2E  1.44269504088896f
#define LN2    0.69314718055995f
#define COLSB  272                 // padded LDS bytes per staged 256-B row

typedef __attribute__((ext_vector_type(8))) short bf16x8;
typedef __attribute__((ext_vector_type(4))) float f32x4;

#if __has_builtin(__builtin_amdgcn_exp2f)
#define EXP2(x) __builtin_amdgcn_exp2f(x)
#else
#define EXP2(x) exp2f(x)
#endif
#if __has_builtin(__builtin_amdgcn_logf)
#define LOG2(x) __builtin_amdgcn_logf(x)
#else
#define LOG2(x) log2f(x)
#endif

static __device__ __forceinline__ unsigned short f2bf(float f) {
    union { float f; unsigned int u; } x;
    x.f = f;
    unsigned int r = ((x.u >> 16) & 1u) + 0x7FFFu;  // round-to-nearest-even
    return (unsigned short)((x.u + r) >> 16);
}

// Kernel 1: E (fp32) -> bf16 in ws; zero ticket counter.
__global__ void prep_kernel(const float* __restrict__ E,
                            unsigned short* __restrict__ Eb,
                            unsigned int* __restrict__ counter) {
    int idx = blockIdx.x * 256 + threadIdx.x;   // 262144 threads, 4 elems each
    float4 v = ((const float4*)E)[idx];
    ushort4 o;
    o.x = f2bf(v.x); o.y = f2bf(v.y); o.z = f2bf(v.z); o.w = f2bf(v.w);
    ((ushort4*)Eb)[idx] = o;
    if (idx == 0) *counter = 0u;
}

// Kernel 2 (R10): COALESCED staging of BOTH tiles through LDS.
// R9 post-mortem: atomics exonerated (90.9->90.0 neutral). Transaction
// arithmetic: old per-lane gathers (B: 128-B lane stride -> 64 separate 16-B
// L2 transactions per wave-instr; A: half-line row gathers) burned ~2600
// 128-B L2 line-slots per block = ~690 MB device-wide = ~20 us at L2 BW.
// Fix: thread tid loads contiguous tid*16 sweeps (1 KB/wave-instr, perfect
// coalescing) of the A-row-block AND B-row-block into LDS (row stride 272 B:
// staging writes and MFMA-layout b128 reads are both bank-balanced, 8/bank).
// Per-block line traffic 2600 -> ~515. Diag blocks alias B onto A.
// LDS ~71 KB -> 2 blocks/CU (LDS-limited, so VGPR pressure is free).
// Kept: one pre-compute barrier (R8), rolled s-loop (R4), no min-waves
// bound (R2), zero global atomics / plain-store part planes (R9).
__global__ __launch_bounds__(256) void fused_kernel(
        const unsigned short* __restrict__ Eb,
        const int* __restrict__ labels,
        float* __restrict__ part) {
    __shared__ __align__(16) char aA[128 * COLSB];   // 34816 B
    __shared__ __align__(16) char bB[128 * COLSB];   // 34816 B
    __shared__ int   labC[128];
    __shared__ int   labR[128];
    __shared__ float colacc[128];

    const int tid  = threadIdx.x;
    const int wid  = tid >> 6;     // 0..3
    const int lane = tid & 63;
    const int q = lane >> 4;       // 0..3
    const int l = lane & 15;       // 0..15

    // Triangular tile decode b -> (r, c), r <= c, 64 row-tiles (128 wide).
    const int b = blockIdx.x;
    int r = (int)(64.5f - sqrtf(64.5f * 64.5f - 2.0f * (float)b));
    while ((r + 1) * 64 - ((r + 1) * r) / 2 <= b) ++r;
    while (r * 64 - (r * (r - 1)) / 2 > b) --r;
    const int c = r + (b - (r * 64 - (r * (r - 1)) / 2));
    const bool diag = (r == c);
    const int tile_m0 = r * 128;
    const int n_begin = c * 128;
    const int mrow0 = wid * 32;            // wave's row strip within tile

    // ---- coalesced staging: thread tid covers bytes [i*4096 + tid*16) ----
    // tile row = i*16 + (tid>>4), row byte = (tid&15)*16.
    const char* gA = (const char*)Eb + (size_t)tile_m0 * 256;
    const char* gB = (const char*)Eb + (size_t)n_begin * 256;
    const int lrow_st = (tid >> 4);        // row offset within a sweep
    const int loff_st = (tid & 15) * 16;
#pragma unroll
    for (int i = 0; i < 16; ++i) {
        float4 v = *(const float4*)(gA + i * 4096 + tid * 16);
        *(float4*)(aA + (i * 16 + lrow_st) * COLSB + loff_st) = v;
    }
    if (!diag) {
#pragma unroll
        for (int i = 0; i < 16; ++i) {
            float4 v = *(const float4*)(gB + i * 4096 + tid * 16);
            *(float4*)(bB + (i * 16 + lrow_st) * COLSB + loff_st) = v;
        }
    }
    if (tid < 128) { labC[tid] = labels[n_begin + tid]; colacc[tid] = 0.0f; }
    else           { labR[tid - 128] = labels[tile_m0 + (tid - 128)]; }
    __syncthreads();   // the ONLY barrier before compute

    const char* bBp = diag ? aA : bB;

    // A fragments from LDS (reused across all 8 subtiles):
    // a[g][kk] = rows mrow0+g*16+l, bytes kk*64 + q*16  (bank-balanced)
    bf16x8 a[2][4];
#pragma unroll
    for (int g = 0; g < 2; ++g)
#pragma unroll
        for (int kk = 0; kk < 4; ++kk)
            a[g][kk] = *(const bf16x8*)(aA + (mrow0 + g * 16 + l) * COLSB + kk * 64 + q * 16);

    int lrow[8];
#pragma unroll
    for (int g = 0; g < 2; ++g)
#pragma unroll
        for (int rr = 0; rr < 4; ++rr)
            lrow[g * 4 + rr] = labR[mrow0 + g * 16 + q * 4 + rr];

    float sum[8];
#pragma unroll
    for (int i = 0; i < 8; ++i) sum[i] = 0.0f;

    // ---- compute: 8 subtiles of 16 cols, all from LDS ----
#pragma clang loop unroll(disable)
    for (int s = 0; s < 8; ++s) {
        const int lc = labC[s * 16 + l];
        const char* lb = bBp + (s * 16 + l) * COLSB + q * 16;
        bf16x8 b0 = *(const bf16x8*)(lb);
        bf16x8 b1 = *(const bf16x8*)(lb + 64);
        bf16x8 b2 = *(const bf16x8*)(lb + 128);
        bf16x8 b3 = *(const bf16x8*)(lb + 192);

        f32x4 acc0 = (f32x4){0.f, 0.f, 0.f, 0.f};
        f32x4 acc1 = (f32x4){0.f, 0.f, 0.f, 0.f};
        acc0 = __builtin_amdgcn_mfma_f32_16x16x32_bf16(a[0][0], b0, acc0, 0, 0, 0);
        acc0 = __builtin_amdgcn_mfma_f32_16x16x32_bf16(a[0][1], b1, acc0, 0, 0, 0);
        acc0 = __builtin_amdgcn_mfma_f32_16x16x32_bf16(a[0][2], b2, acc0, 0, 0, 0);
        acc0 = __builtin_amdgcn_mfma_f32_16x16x32_bf16(a[0][3], b3, acc0, 0, 0, 0);
        acc1 = __builtin_amdgcn_mfma_f32_16x16x32_bf16(a[1][0], b0, acc1, 0, 0, 0);
        acc1 = __builtin_amdgcn_mfma_f32_16x16x32_bf16(a[1][1], b1, acc1, 0, 0, 0);
        acc1 = __builtin_amdgcn_mfma_f32_16x16x32_bf16(a[1][2], b2, acc1, 0, 0, 0);
        acc1 = __builtin_amdgcn_mfma_f32_16x16x32_bf16(a[1][3], b3, acc1, 0, 0, 0);

        float cp = 0.0f;
#pragma unroll
        for (int g = 0; g < 2; ++g) {
#pragma unroll
            for (int rr = 0; rr < 4; ++rr) {
                float sv = (g == 0) ? acc0[rr] : acc1[rr];
                bool eq = (lrow[g * 4 + rr] == lc);
                float cc = eq ? -LOG2E : LOG2E;
                float term = EXP2(cc * (sv - 0.1f));
                sum[g * 4 + rr] += term;
                cp += term;
            }
        }
        if (!diag) {
            cp += __shfl_xor(cp, 16);   // reduce over q-quarters
            cp += __shfl_xor(cp, 32);
            if (q == 0) atomicAdd(&colacc[s * 16 + l], cp);  // LDS only
        }
    }

    // Row credits: reduce across the 16 column-lanes, PLAIN stores, plane c.
#pragma unroll
    for (int i = 0; i < 8; ++i) {
        float v = sum[i];
        v += __shfl_xor(v, 1);
        v += __shfl_xor(v, 2);
        v += __shfl_xor(v, 4);
        v += __shfl_xor(v, 8);
        sum[i] = v;
    }
    if (l == 0) {
#pragma unroll
        for (int g = 0; g < 2; ++g)
#pragma unroll
            for (int rr = 0; rr < 4; ++rr)
                part[(size_t)c * N + tile_m0 + mrow0 + g * 16 + q * 4 + rr] = sum[g * 4 + rr];
    }

    // Col credits: PLAIN stores to plane r (off-diagonal only).
    __syncthreads();
    if (!diag && tid < 128)
        part[(size_t)r * N + n_begin + tid] = colacc[tid];
}

// Kernel 3: rowsum_i = sum over 64 planes; log; block-reduce; ticketed final.
__global__ void finalize_kernel(const float* __restrict__ part,
                                float* __restrict__ bpart,
                                unsigned int* __restrict__ counter,
                                float* __restrict__ out) {
    __shared__ float red[4];
    __shared__ unsigned int tk;
    const int tid = threadIdx.x;
    const int i = blockIdx.x * 256 + tid;

    float s = 0.0f;
#pragma unroll 8
    for (int x = 0; x < 64; ++x) s += part[(size_t)x * N + i];
    float v = LOG2(s) * LN2;
#pragma unroll
    for (int off = 1; off <= 32; off <<= 1) v += __shfl_xor(v, off);
    if ((tid & 63) == 0) red[tid >> 6] = v;
    __syncthreads();
    if (tid == 0) {
        bpart[blockIdx.x] = red[0] + red[1] + red[2] + red[3];
        __threadfence();                       // release bpart store
        tk = atomicAdd(counter, 1u);
    }
    __syncthreads();
    if (tk == 31u) {                           // last block finalizes
        __threadfence();                       // acquire
        if (tid < 64) {
            float t = (tid < 32)
                ? __hip_atomic_load(&bpart[tid], __ATOMIC_RELAXED,
                                    __HIP_MEMORY_SCOPE_AGENT)
                : 0.0f;
#pragma unroll
            for (int off = 1; off <= 32; off <<= 1) t += __shfl_xor(t, off);
            if (tid == 0) out[0] = t * (1.0f / (float)N);
        }
    }
}

extern "C" void kernel_launch(void* const* d_in, const int* in_sizes, int n_in,
                              void* d_out, int out_size, void* d_ws, size_t ws_size,
                              hipStream_t stream) {
    const float* E = (const float*)d_in[0];
    const int* labels = (const int*)d_in[1];
    float* out = (float*)d_out;

    unsigned short* Eb = (unsigned short*)d_ws;                 // 2 MiB
    float* part = (float*)((char*)d_ws + (size_t)N * D * 2);    // 64*8192*4 = 2 MiB
    float* bpart = part + (size_t)64 * N;                       // 32 floats
    unsigned int* counter = (unsigned int*)(bpart + 32);        // 4 B

    prep_kernel<<<1024, 256, 0, stream>>>(E, Eb, counter);
    fused_kernel<<<2080, 256, 0, stream>>>(Eb, labels, part);
    finalize_kernel<<<32, 256, 0, stream>>>(part, bpart, counter, out);
}

// Round 11
// 83.746 us; speedup vs baseline: 1.1802x; 1.1802x over previous
//
#include <hip/hip_runtime.h>
#include <hip/hip_bf16.h>

#define N 8192
#define D 128
#define LOG2E  1.44269504088896f
#define LN2    0.69314718055995f

typedef __attribute__((ext_vector_type(8))) short bf16x8;
typedef __attribute__((ext_vector_type(4))) float f32x4;

#if __has_builtin(__builtin_amdgcn_exp2f)
#define EXP2(x) __builtin_amdgcn_exp2f(x)
#else
#define EXP2(x) exp2f(x)
#endif
#if __has_builtin(__builtin_amdgcn_logf)
#define LOG2(x) __builtin_amdgcn_logf(x)
#else
#define LOG2(x) log2f(x)
#endif

static __device__ __forceinline__ unsigned short f2bf(float f) {
    union { float f; unsigned int u; } x;
    x.f = f;
    unsigned int r = ((x.u >> 16) & 1u) + 0x7FFFu;  // round-to-nearest-even
    return (unsigned short)((x.u + r) >> 16);
}

// Kernel 1 (R11): E (fp32) -> Eb2 (bf16) in FRAGMENT-MAJOR layout.
// MFMA 16x16x32 A- and B-operands share one lane map: lane(q*16+l) holds
// row 16S+l, k-chunk kk, bytes q*16. Store chunk (S,kk,lane) at byte
// S*4096 + kk*1024 + lane*16. Then every frag load in fused is ONE
// contiguous 1-KB wave-load (8 line transactions, zero amplification,
// no LDS round-trip needed). 131072 threads, one 16-B output chunk each;
// writes perfectly coalesced, reads 16-row x 128-B sweeps (LLC-warm E).
__global__ void prep_kernel(const float* __restrict__ E,
                            uint4* __restrict__ Eb2,
                            unsigned int* __restrict__ counter) {
    const int j = blockIdx.x * 256 + threadIdx.x;   // 0..131071
    const int l  = j & 15;
    const int q  = (j >> 4) & 3;
    const int kk = (j >> 6) & 3;
    const int S  = j >> 8;
    const float4* src = (const float4*)(E + (size_t)(S * 16 + l) * D + kk * 32 + q * 8);
    float4 f0 = src[0], f1 = src[1];
    uint4 o;
    o.x = f2bf(f0.x) | ((unsigned)f2bf(f0.y) << 16);
    o.y = f2bf(f0.z) | ((unsigned)f2bf(f0.w) << 16);
    o.z = f2bf(f1.x) | ((unsigned)f2bf(f1.y) << 16);
    o.w = f2bf(f1.z) | ((unsigned)f2bf(f1.w) << 16);
    Eb2[j] = o;
    if (j == 0) *counter = 0u;
}

// Kernel 2 (R11): direct register fragment loads from fragment-major Eb2.
// Suspect ledger: work volume (R7), barriers (R8), global atomics (R9) all
// exonerated; R10's coalescing-via-LDS was confounded by 2-blocks/CU.
// This round: zero tile LDS (only 1.5 KB labels/colacc -> occupancy is
// VGPR-bound, ~16-20 waves/CU), zero amplification (every A/B frag = one
// contiguous 1-KB wave-load). Triangular symmetry + plane-store epilogue
// kept from R9. s-loop pinned rolled (R4); no min-waves bound (R2).
__global__ __launch_bounds__(256) void fused_kernel(
        const unsigned short* __restrict__ Eb2,
        const int* __restrict__ labels,
        float* __restrict__ part) {
    __shared__ int   labC[128];
    __shared__ int   labR[128];
    __shared__ float colacc[128];

    const int tid  = threadIdx.x;
    const int wid  = tid >> 6;     // 0..3
    const int lane = tid & 63;
    const int q = lane >> 4;       // 0..3
    const int l = lane & 15;       // 0..15

    // Triangular tile decode b -> (r, c), r <= c, 64 row-tiles (128 wide).
    const int b = blockIdx.x;
    int r = (int)(64.5f - sqrtf(64.5f * 64.5f - 2.0f * (float)b));
    while ((r + 1) * 64 - ((r + 1) * r) / 2 <= b) ++r;
    while (r * 64 - (r * (r - 1)) / 2 > b) --r;
    const int c = r + (b - (r * 64 - (r * (r - 1)) / 2));
    const bool diag = (r == c);
    const int tile_m0 = r * 128;
    const int n_begin = c * 128;
    const int mrow0 = wid * 32;            // wave's row strip within tile

    const char* base = (const char*)Eb2;

    // A fragments: row-group S_A = r*8 + wid*2 + g. Contiguous 1-KB wave-loads.
    bf16x8 a[2][4];
#pragma unroll
    for (int g = 0; g < 2; ++g) {
        const char* pa = base + (size_t)(r * 8 + wid * 2 + g) * 4096 + lane * 16;
#pragma unroll
        for (int kk = 0; kk < 4; ++kk)
            a[g][kk] = *(const bf16x8*)(pa + kk * 1024);
    }

    if (tid < 128) { labC[tid] = labels[n_begin + tid]; colacc[tid] = 0.0f; }
    else           { labR[tid - 128] = labels[tile_m0 + (tid - 128)]; }
    __syncthreads();

    int lrow[8];
#pragma unroll
    for (int g = 0; g < 2; ++g)
#pragma unroll
        for (int rr = 0; rr < 4; ++rr)
            lrow[g * 4 + rr] = labR[mrow0 + g * 16 + q * 4 + rr];

    float sum[8];
#pragma unroll
    for (int i = 0; i < 8; ++i) sum[i] = 0.0f;

    // ---- compute: 8 subtiles of 16 cols; B frags direct from Eb2 ----
#pragma clang loop unroll(disable)
    for (int s = 0; s < 8; ++s) {
        const char* pb = base + (size_t)(c * 8 + s) * 4096 + lane * 16;
        bf16x8 b0 = *(const bf16x8*)(pb);
        bf16x8 b1 = *(const bf16x8*)(pb + 1024);
        bf16x8 b2 = *(const bf16x8*)(pb + 2048);
        bf16x8 b3 = *(const bf16x8*)(pb + 3072);
        const int lc = labC[s * 16 + l];

        f32x4 acc0 = (f32x4){0.f, 0.f, 0.f, 0.f};
        f32x4 acc1 = (f32x4){0.f, 0.f, 0.f, 0.f};
        acc0 = __builtin_amdgcn_mfma_f32_16x16x32_bf16(a[0][0], b0, acc0, 0, 0, 0);
        acc0 = __builtin_amdgcn_mfma_f32_16x16x32_bf16(a[0][1], b1, acc0, 0, 0, 0);
        acc0 = __builtin_amdgcn_mfma_f32_16x16x32_bf16(a[0][2], b2, acc0, 0, 0, 0);
        acc0 = __builtin_amdgcn_mfma_f32_16x16x32_bf16(a[0][3], b3, acc0, 0, 0, 0);
        acc1 = __builtin_amdgcn_mfma_f32_16x16x32_bf16(a[1][0], b0, acc1, 0, 0, 0);
        acc1 = __builtin_amdgcn_mfma_f32_16x16x32_bf16(a[1][1], b1, acc1, 0, 0, 0);
        acc1 = __builtin_amdgcn_mfma_f32_16x16x32_bf16(a[1][2], b2, acc1, 0, 0, 0);
        acc1 = __builtin_amdgcn_mfma_f32_16x16x32_bf16(a[1][3], b3, acc1, 0, 0, 0);

        float cp = 0.0f;
#pragma unroll
        for (int g = 0; g < 2; ++g) {
#pragma unroll
            for (int rr = 0; rr < 4; ++rr) {
                float sv = (g == 0) ? acc0[rr] : acc1[rr];
                bool eq = (lrow[g * 4 + rr] == lc);
                float cc = eq ? -LOG2E : LOG2E;
                float term = EXP2(cc * (sv - 0.1f));
                sum[g * 4 + rr] += term;
                cp += term;
            }
        }
        if (!diag) {
            cp += __shfl_xor(cp, 16);   // reduce over q-quarters
            cp += __shfl_xor(cp, 32);
            if (q == 0) atomicAdd(&colacc[s * 16 + l], cp);  // LDS only
        }
    }

    // Row credits: reduce across the 16 column-lanes, PLAIN stores, plane c.
#pragma unroll
    for (int i = 0; i < 8; ++i) {
        float v = sum[i];
        v += __shfl_xor(v, 1);
        v += __shfl_xor(v, 2);
        v += __shfl_xor(v, 4);
        v += __shfl_xor(v, 8);
        sum[i] = v;
    }
    if (l == 0) {
#pragma unroll
        for (int g = 0; g < 2; ++g)
#pragma unroll
            for (int rr = 0; rr < 4; ++rr)
                part[(size_t)c * N + tile_m0 + mrow0 + g * 16 + q * 4 + rr] = sum[g * 4 + rr];
    }

    // Col credits: PLAIN stores to plane r (off-diagonal only).
    __syncthreads();
    if (!diag && tid < 128)
        part[(size_t)r * N + n_begin + tid] = colacc[tid];
}

// Kernel 3: rowsum_i = sum over 64 planes; log; block-reduce; ticketed final.
__global__ void finalize_kernel(const float* __restrict__ part,
                                float* __restrict__ bpart,
                                unsigned int* __restrict__ counter,
                                float* __restrict__ out) {
    __shared__ float red[4];
    __shared__ unsigned int tk;
    const int tid = threadIdx.x;
    const int i = blockIdx.x * 256 + tid;

    float s = 0.0f;
#pragma unroll 8
    for (int x = 0; x < 64; ++x) s += part[(size_t)x * N + i];
    float v = LOG2(s) * LN2;
#pragma unroll
    for (int off = 1; off <= 32; off <<= 1) v += __shfl_xor(v, off);
    if ((tid & 63) == 0) red[tid >> 6] = v;
    __syncthreads();
    if (tid == 0) {
        bpart[blockIdx.x] = red[0] + red[1] + red[2] + red[3];
        __threadfence();                       // release bpart store
        tk = atomicAdd(counter, 1u);
    }
    __syncthreads();
    if (tk == 31u) {                           // last block finalizes
        __threadfence();                       // acquire
        if (tid < 64) {
            float t = (tid < 32)
                ? __hip_atomic_load(&bpart[tid], __ATOMIC_RELAXED,
                                    __HIP_MEMORY_SCOPE_AGENT)
                : 0.0f;
#pragma unroll
            for (int off = 1; off <= 32; off <<= 1) t += __shfl_xor(t, off);
            if (tid == 0) out[0] = t * (1.0f / (float)N);
        }
    }
}

extern "C" void kernel_launch(void* const* d_in, const int* in_sizes, int n_in,
                              void* d_out, int out_size, void* d_ws, size_t ws_size,
                              hipStream_t stream) {
    const float* E = (const float*)d_in[0];
    const int* labels = (const int*)d_in[1];
    float* out = (float*)d_out;

    unsigned short* Eb2 = (unsigned short*)d_ws;                // 2 MiB, fragment-major
    float* part = (float*)((char*)d_ws + (size_t)N * D * 2);    // 64*8192*4 = 2 MiB
    float* bpart = part + (size_t)64 * N;                       // 32 floats
    unsigned int* counter = (unsigned int*)(bpart + 32);        // 4 B

    prep_kernel<<<512, 256, 0, stream>>>(E, (uint4*)Eb2, counter);
    fused_kernel<<<2080, 256, 0, stream>>>(Eb2, labels, part);
    finalize_kernel<<<32, 256, 0, stream>>>(part, bpart, counter, out);
}